// Round 1
// baseline (82.389 us; speedup 1.0000x reference)
//
#include <hip/hip_runtime.h>

// speed[n,d] = sum_{f,m} Cont[f] * exp(-||P[n]-S[f,m]||^2) * V[f,m,d]
// Refactor exponent: exp(-d2) = exp2( (2*xy - x2 - s2) * log2e )
//   = exp2( dot(p, K2*s) + (-K1*x2) + (-K1*s2) ),  K1=log2e, K2=2*log2e
// Packed entry (32B): [K2*sx, K2*sy, K2*sz, -K1*s2] [c*vx, c*vy, c*vz, 0]

#define K1f 1.4426950408889634f
#define K2f 2.8853900817779268f

constexpr int N_PTS  = 65536;
constexpr int MM     = 512;
constexpr int FM     = 4096;          // F*M
constexpr int SPLITS = 16;
constexpr int CHUNK  = FM / SPLITS;   // 256 entries per block
constexpr int PPT    = 8;             // points per thread
constexpr int BLK    = 256;
constexpr int TILE   = BLK * PPT;     // 2048 points per block
constexpr int NTILES = N_PTS / TILE;  // 32

__global__ __launch_bounds__(256) void pack_kernel(
    const float* __restrict__ supp_pts, const float* __restrict__ supp_vec,
    const float* __restrict__ Cont, float4* __restrict__ packed) {
  int e = blockIdx.x * blockDim.x + threadIdx.x;
  if (e >= FM) return;
  int f = e / MM;
  float sx = supp_pts[e * 3 + 0];
  float sy = supp_pts[e * 3 + 1];
  float sz = supp_pts[e * 3 + 2];
  float c  = Cont[f];
  float s2 = sx * sx + sy * sy + sz * sz;
  packed[2 * e + 0] = make_float4(K2f * sx, K2f * sy, K2f * sz, -K1f * s2);
  packed[2 * e + 1] = make_float4(c * supp_vec[e * 3 + 0],
                                  c * supp_vec[e * 3 + 1],
                                  c * supp_vec[e * 3 + 2], 0.0f);
}

__global__ __launch_bounds__(256) void speed_kernel(
    const float* __restrict__ Points, const float4* __restrict__ packed,
    float* __restrict__ out) {
  __shared__ float4 lds[CHUNK * 2];   // 8 KB

  const int tid   = threadIdx.x;
  const int tile  = blockIdx.x / SPLITS;
  const int split = blockIdx.x % SPLITS;

  // Stage this split's chunk of packed support data into LDS.
  const float4* src = packed + (size_t)split * (CHUNK * 2);
  for (int i = tid; i < CHUNK * 2; i += BLK) lds[i] = src[i];

  // Load 8 points per thread.
  float px[PPT], py[PPT], pz[PPT], xe[PPT];
  float ax[PPT], ay[PPT], az[PPT];
  const int base = tile * TILE + tid;
#pragma unroll
  for (int k = 0; k < PPT; ++k) {
    int n = base + k * BLK;
    float x = Points[n * 3 + 0];
    float y = Points[n * 3 + 1];
    float z = Points[n * 3 + 2];
    px[k] = x; py[k] = y; pz[k] = z;
    xe[k] = -K1f * (x * x + y * y + z * z);
    ax[k] = 0.0f; ay[k] = 0.0f; az[k] = 0.0f;
  }
  __syncthreads();

#pragma unroll 4
  for (int e = 0; e < CHUNK; ++e) {
    float4 a = lds[2 * e + 0];   // broadcast: all lanes same address
    float4 b = lds[2 * e + 1];
#pragma unroll
    for (int k = 0; k < PPT; ++k) {
      float h = fmaf(px[k], a.x, xe[k]);
      h = fmaf(py[k], a.y, h);
      h = fmaf(pz[k], a.z, h);
      float w = __builtin_amdgcn_exp2f(h + a.w);  // v_exp_f32
      ax[k] = fmaf(w, b.x, ax[k]);
      ay[k] = fmaf(w, b.y, ay[k]);
      az[k] = fmaf(w, b.z, az[k]);
    }
  }

#pragma unroll
  for (int k = 0; k < PPT; ++k) {
    int n = base + k * BLK;
    unsafeAtomicAdd(&out[n * 3 + 0], ax[k]);
    unsafeAtomicAdd(&out[n * 3 + 1], ay[k]);
    unsafeAtomicAdd(&out[n * 3 + 2], az[k]);
  }
}

extern "C" void kernel_launch(void* const* d_in, const int* in_sizes, int n_in,
                              void* d_out, int out_size, void* d_ws, size_t ws_size,
                              hipStream_t stream) {
  const float* Points   = (const float*)d_in[0];
  const float* supp_pts = (const float*)d_in[1];
  const float* supp_vec = (const float*)d_in[2];
  const float* Cont     = (const float*)d_in[3];
  float* out = (float*)d_out;
  float4* packed = (float4*)d_ws;   // 4096 * 32B = 128 KB scratch

  hipMemsetAsync(d_out, 0, (size_t)out_size * sizeof(float), stream);
  pack_kernel<<<FM / 256, 256, 0, stream>>>(supp_pts, supp_vec, Cont, packed);
  speed_kernel<<<NTILES * SPLITS, BLK, 0, stream>>>(Points, packed, out);
}

// Round 2
// 67.637 us; speedup vs baseline: 1.2181x; 1.2181x over previous
//
#include <hip/hip_runtime.h>

// speed[n,d] = sum_{f,m} Cont[f] * exp(-||P[n]-S[f,m]||^2) * V[f,m,d]
// exp(-d2) = exp2( dot(p, K2*s) - K1*x2 - K1*s2 ),  K1=log2e, K2=2*log2e
// Packed entry (32B): [K2*sx, K2*sy, K2*sz, -K1*s2] [c*vx, c*vy, c*vz, 0]

typedef float v2f __attribute__((ext_vector_type(2)));

#define K1f 1.4426950408889634f
#define K2f 2.8853900817779268f

constexpr int N_PTS  = 65536;
constexpr int MM     = 512;
constexpr int FM     = 4096;          // F*M
constexpr int SPLITS = 16;
constexpr int CHUNK  = FM / SPLITS;   // 256 entries per block
constexpr int PPT    = 2;             // points per thread (one v2f lane-pair)
constexpr int BLK    = 256;
constexpr int TILE   = BLK * PPT;     // 512 points per block
constexpr int NTILES = N_PTS / TILE;  // 128

__global__ __launch_bounds__(256) void pack_kernel(
    const float* __restrict__ supp_pts, const float* __restrict__ supp_vec,
    const float* __restrict__ Cont, float4* __restrict__ packed) {
  int e = blockIdx.x * blockDim.x + threadIdx.x;
  if (e >= FM) return;
  int f = e / MM;
  float sx = supp_pts[e * 3 + 0];
  float sy = supp_pts[e * 3 + 1];
  float sz = supp_pts[e * 3 + 2];
  float c  = Cont[f];
  float s2 = sx * sx + sy * sy + sz * sz;
  packed[2 * e + 0] = make_float4(K2f * sx, K2f * sy, K2f * sz, -K1f * s2);
  packed[2 * e + 1] = make_float4(c * supp_vec[e * 3 + 0],
                                  c * supp_vec[e * 3 + 1],
                                  c * supp_vec[e * 3 + 2], 0.0f);
}

__global__ __launch_bounds__(BLK, 8) void speed_kernel(
    const float* __restrict__ Points, const float4* __restrict__ packed,
    float* __restrict__ out) {
  __shared__ float4 lds[CHUNK * 2];   // 8 KB

  const int tid   = threadIdx.x;
  const int tile  = blockIdx.x / SPLITS;
  const int split = blockIdx.x % SPLITS;

  // Stage this split's chunk of packed support data into LDS.
  const float4* src = packed + (size_t)split * (CHUNK * 2);
  for (int i = tid; i < CHUNK * 2; i += BLK) lds[i] = src[i];

  // Two points per thread, held as lane-pairs in v2f for v_pk_fma_f32.
  const int n0 = tile * TILE + tid;
  const int n1 = n0 + BLK;
  float x0 = Points[n0 * 3 + 0], y0 = Points[n0 * 3 + 1], z0 = Points[n0 * 3 + 2];
  float x1 = Points[n1 * 3 + 0], y1 = Points[n1 * 3 + 1], z1 = Points[n1 * 3 + 2];
  v2f px = {x0, x1}, py = {y0, y1}, pz = {z0, z1};
  v2f xe = {-K1f * (x0 * x0 + y0 * y0 + z0 * z0),
            -K1f * (x1 * x1 + y1 * y1 + z1 * z1)};
  v2f ax = {0.0f, 0.0f}, ay = {0.0f, 0.0f}, az = {0.0f, 0.0f};
  __syncthreads();

#pragma unroll 4
  for (int e = 0; e < CHUNK; ++e) {
    float4 a = lds[2 * e + 0];   // broadcast reads: conflict-free
    float4 b = lds[2 * e + 1];
    v2f sax = a.x, say = a.y, saz = a.z, saw = a.w;
    v2f t = xe + saw;
    t = __builtin_elementwise_fma(px, sax, t);
    t = __builtin_elementwise_fma(py, say, t);
    t = __builtin_elementwise_fma(pz, saz, t);
    v2f w = {__builtin_amdgcn_exp2f(t.x), __builtin_amdgcn_exp2f(t.y)};
    v2f sbx = b.x, sby = b.y, sbz = b.z;
    ax = __builtin_elementwise_fma(w, sbx, ax);
    ay = __builtin_elementwise_fma(w, sby, ay);
    az = __builtin_elementwise_fma(w, sbz, az);
  }

  unsafeAtomicAdd(&out[n0 * 3 + 0], ax.x);
  unsafeAtomicAdd(&out[n0 * 3 + 1], ay.x);
  unsafeAtomicAdd(&out[n0 * 3 + 2], az.x);
  unsafeAtomicAdd(&out[n1 * 3 + 0], ax.y);
  unsafeAtomicAdd(&out[n1 * 3 + 1], ay.y);
  unsafeAtomicAdd(&out[n1 * 3 + 2], az.y);
}

extern "C" void kernel_launch(void* const* d_in, const int* in_sizes, int n_in,
                              void* d_out, int out_size, void* d_ws, size_t ws_size,
                              hipStream_t stream) {
  const float* Points   = (const float*)d_in[0];
  const float* supp_pts = (const float*)d_in[1];
  const float* supp_vec = (const float*)d_in[2];
  const float* Cont     = (const float*)d_in[3];
  float* out = (float*)d_out;
  float4* packed = (float4*)d_ws;   // 4096 * 32B = 128 KB scratch

  hipMemsetAsync(d_out, 0, (size_t)out_size * sizeof(float), stream);
  pack_kernel<<<FM / 256, 256, 0, stream>>>(supp_pts, supp_vec, Cont, packed);
  speed_kernel<<<NTILES * SPLITS, BLK, 0, stream>>>(Points, packed, out);
}

// Round 3
// 53.455 us; speedup vs baseline: 1.5413x; 1.2653x over previous
//
#include <hip/hip_runtime.h>

// speed[n,d] = sum_{f,m} Cont[f] * exp(-||P[n]-S[f,m]||^2) * V[f,m,d]
// Split the exponent:
//   exp(-d2) = exp2( (2xy - x2)*log2e ) * exp(-s2)
// Precompute per entry:  a = K2*s  (K2 = 2*log2e),  b = c*v*exp(-s2)
// Per point:             xe = -K1*x2  (K1 = log2e)
// Per interaction: w = exp2( fma(px,ax, fma(py,ay, fma(pz,az, xe))) );
//                  acc += w * b        -> 6 FMA-class VALU + 1 trans.
// Support data is wave-uniform -> lives in SGPRs via scalar loads (no LDS).

typedef float v2f __attribute__((ext_vector_type(2)));

#define K1f 1.4426950408889634f
#define K2f 2.8853900817779268f

constexpr int N_PTS  = 65536;
constexpr int MM     = 512;
constexpr int FM     = 4096;          // F*M
constexpr int SPLITS = 16;
constexpr int CHUNK  = FM / SPLITS;   // 256 entries per block
constexpr int PPT    = 2;             // points per thread (one v2f pair)
constexpr int BLK    = 256;
constexpr int TILE   = BLK * PPT;     // 512 points per block
constexpr int NTILES = N_PTS / TILE;  // 128

__global__ __launch_bounds__(256) void pack_kernel(
    const float* __restrict__ supp_pts, const float* __restrict__ supp_vec,
    const float* __restrict__ Cont, float4* __restrict__ packed) {
  int e = blockIdx.x * blockDim.x + threadIdx.x;
  if (e >= FM) return;
  int f = e / MM;
  float sx = supp_pts[e * 3 + 0];
  float sy = supp_pts[e * 3 + 1];
  float sz = supp_pts[e * 3 + 2];
  float c  = Cont[f];
  float s2 = sx * sx + sy * sy + sz * sz;
  float g  = c * __expf(-s2);   // fold exp(-s2) and Cont into the vector
  packed[2 * e + 0] = make_float4(K2f * sx, K2f * sy, K2f * sz, 0.0f);
  packed[2 * e + 1] = make_float4(g * supp_vec[e * 3 + 0],
                                  g * supp_vec[e * 3 + 1],
                                  g * supp_vec[e * 3 + 2], 0.0f);
}

__global__ __launch_bounds__(BLK, 8) void speed_kernel(
    const float* __restrict__ Points, const float4* __restrict__ packed,
    float* __restrict__ out) {
  const int tid   = threadIdx.x;
  const int tile  = blockIdx.x / SPLITS;
  const int split = blockIdx.x % SPLITS;

  // Two points per thread as lane-pairs (v2f -> v_pk_fma_f32).
  const int n0 = tile * TILE + tid;
  const int n1 = n0 + BLK;
  float x0 = Points[n0 * 3 + 0], y0 = Points[n0 * 3 + 1], z0 = Points[n0 * 3 + 2];
  float x1 = Points[n1 * 3 + 0], y1 = Points[n1 * 3 + 1], z1 = Points[n1 * 3 + 2];
  v2f px = {x0, x1}, py = {y0, y1}, pz = {z0, z1};
  v2f xe = {-K1f * (x0 * x0 + y0 * y0 + z0 * z0),
            -K1f * (x1 * x1 + y1 * y1 + z1 * z1)};
  v2f ax = {0.0f, 0.0f}, ay = {0.0f, 0.0f}, az = {0.0f, 0.0f};

  // Wave-uniform address -> scalar loads (SGPR-resident support data).
  const float4* sp = packed + (size_t)split * (CHUNK * 2);

#pragma unroll 8
  for (int e = 0; e < CHUNK; ++e) {
    float4 a = sp[2 * e + 0];
    float4 b = sp[2 * e + 1];
    v2f t = xe;
    t = __builtin_elementwise_fma(px, (v2f){a.x, a.x}, t);
    t = __builtin_elementwise_fma(py, (v2f){a.y, a.y}, t);
    t = __builtin_elementwise_fma(pz, (v2f){a.z, a.z}, t);
    v2f w = {__builtin_amdgcn_exp2f(t.x), __builtin_amdgcn_exp2f(t.y)};
    ax = __builtin_elementwise_fma(w, (v2f){b.x, b.x}, ax);
    ay = __builtin_elementwise_fma(w, (v2f){b.y, b.y}, ay);
    az = __builtin_elementwise_fma(w, (v2f){b.z, b.z}, az);
  }

  unsafeAtomicAdd(&out[n0 * 3 + 0], ax.x);
  unsafeAtomicAdd(&out[n0 * 3 + 1], ay.x);
  unsafeAtomicAdd(&out[n0 * 3 + 2], az.x);
  unsafeAtomicAdd(&out[n1 * 3 + 0], ax.y);
  unsafeAtomicAdd(&out[n1 * 3 + 1], ay.y);
  unsafeAtomicAdd(&out[n1 * 3 + 2], az.y);
}

extern "C" void kernel_launch(void* const* d_in, const int* in_sizes, int n_in,
                              void* d_out, int out_size, void* d_ws, size_t ws_size,
                              hipStream_t stream) {
  const float* Points   = (const float*)d_in[0];
  const float* supp_pts = (const float*)d_in[1];
  const float* supp_vec = (const float*)d_in[2];
  const float* Cont     = (const float*)d_in[3];
  float* out = (float*)d_out;
  float4* packed = (float4*)d_ws;   // 4096 * 32B = 128 KB scratch

  hipMemsetAsync(d_out, 0, (size_t)out_size * sizeof(float), stream);
  pack_kernel<<<FM / 256, 256, 0, stream>>>(supp_pts, supp_vec, Cont, packed);
  speed_kernel<<<NTILES * SPLITS, BLK, 0, stream>>>(Points, packed, out);
}